// Round 9
// baseline (925.760 us; speedup 1.0000x reference)
//
#include <hip/hip_runtime.h>
#include <hip/hip_bf16.h>
#include <math.h>

#define T_LEN 512
#define B_SZ  256
#define I_SZ  300
#define H_SZ  64
#define G3    192   // 3H
#define TPG   3072  // 192*16 h16 per t-slice of one group

typedef float    f4v __attribute__((ext_vector_type(4)));
typedef _Float16 h4v __attribute__((ext_vector_type(4)));
typedef _Float16 h8v __attribute__((ext_vector_type(8)));

__device__ __forceinline__ float sigm_f(float x) {
    return __builtin_amdgcn_rcpf(1.f + __expf(-x));
}
__device__ __forceinline__ float tanh_f(float x) {
    float a = fabsf(x);
    float e = __expf(2.f * a);
    float t = 1.f - 2.f * __builtin_amdgcn_rcpf(1.f + e);
    return copysignf(t, x);
}

// ---------------------------------------------------------------------------
// Kernel 1: input projection, f16 MFMA. M-dim = (t-tile, batch-within-tile):
// C row m = batch 0..15, tiles = 8 t's. Output xp2[d][G][t][g][m(16)] matches
// the scan's read pattern (coalesced b64 both sides).
// ---------------------------------------------------------------------------
#define KC  64
#define NKC 5     // ceil(300/64)

__device__ __forceinline__ int stage_off(int j, int srow, int skq) {
    int g2 = (skq >> 1) & 3;
    return j * 1024 + (skq >> 3) * 512 + g2 * 128 + ((srow ^ (g2 << 1)) << 3) + (skq & 1) * 4;
}
__device__ __forceinline__ int frag_off(int tile, int kh, int lane) {
    int kgrp = lane >> 4, fr = lane & 15;
    return tile * 1024 + kh * 512 + kgrp * 128 + (((fr ^ (kgrp << 1))) << 3);
}

__global__ __launch_bounds__(256, 2) void proj_gemm(
    const float* __restrict__ x,
    const float* __restrict__ Wf, const float* __restrict__ bf,
    const float* __restrict__ Wb, const float* __restrict__ bb,
    _Float16* __restrict__ xp)
{
    __shared__ _Float16 Ap[8 * 1024];    // 16 KB  (8 t-tiles x 2 kh x 512)
    __shared__ _Float16 Bp[12 * 1024];   // 24 KB

    const int tid = threadIdx.x;
    const int bid = blockIdx.x;          // 0..2047
    const int d   = bid >> 10;
    const int G   = (bid >> 6) & 15;     // batch group (16 b's)
    const int tc  = bid & 63;            // t-chunk (8 t's)

    const float* W    = d ? Wb : Wf;
    const float* bias = d ? bb : bf;

    const int srow = tid >> 4;           // 0..15  (= batch within group for A)
    const int skq  = tid & 15;           // k-quad (k' = skq*4)

    const int lane = tid & 63;
    const int w    = tid >> 6;           // 0..3
    const int wn   = (w >> 1) * 96;      // wave N offset

    f4v acc[4][6];
    #pragma unroll
    for (int mt = 0; mt < 4; ++mt)
        #pragma unroll
        for (int nt = 0; nt < 6; ++nt) acc[mt][nt] = (f4v)0.f;

    float4 av[8], bv[12];
    // prefetch chunk 0:  A row r = j*16+srow -> t-tile j, batch srow
    {
        const bool valid = (skq * 4) <= 296;
        #pragma unroll
        for (int j = 0; j < 8; ++j)
            av[j] = valid ? *(const float4*)(x + ((size_t)(G * 16 + srow) * T_LEN + tc * 8 + j) * I_SZ + skq * 4)
                          : float4{0.f, 0.f, 0.f, 0.f};
        #pragma unroll
        for (int j = 0; j < 12; ++j)
            bv[j] = valid ? *(const float4*)(W + (size_t)(j * 16 + srow) * I_SZ + skq * 4)
                          : float4{0.f, 0.f, 0.f, 0.f};
    }

    for (int kc = 0; kc < NKC; ++kc) {
        __syncthreads();

        #pragma unroll
        for (int j = 0; j < 8; ++j) {
            h4v c = { (_Float16)av[j].x, (_Float16)av[j].y,
                      (_Float16)av[j].z, (_Float16)av[j].w };
            *(h4v*)&Ap[stage_off(j, srow, skq)] = c;
        }
        #pragma unroll
        for (int j = 0; j < 12; ++j) {
            h4v c = { (_Float16)bv[j].x, (_Float16)bv[j].y,
                      (_Float16)bv[j].z, (_Float16)bv[j].w };
            *(h4v*)&Bp[stage_off(j, srow, skq)] = c;
        }
        __syncthreads();

        if (kc + 1 < NKC) {
            const int k0 = (kc + 1) * KC;
            const bool valid = (k0 + skq * 4) <= 296;
            #pragma unroll
            for (int j = 0; j < 8; ++j)
                av[j] = valid ? *(const float4*)(x + ((size_t)(G * 16 + srow) * T_LEN + tc * 8 + j) * I_SZ + k0 + skq * 4)
                              : float4{0.f, 0.f, 0.f, 0.f};
            #pragma unroll
            for (int j = 0; j < 12; ++j)
                bv[j] = valid ? *(const float4*)(W + (size_t)(j * 16 + srow) * I_SZ + k0 + skq * 4)
                              : float4{0.f, 0.f, 0.f, 0.f};
        }

        #pragma unroll
        for (int kh = 0; kh < 2; ++kh) {
            h8v bh_[6];
            #pragma unroll
            for (int nt = 0; nt < 6; ++nt)
                bh_[nt] = *(const h8v*)&Bp[frag_off((w >> 1) * 6 + nt, kh, lane)];
            #pragma unroll
            for (int mt = 0; mt < 4; ++mt) {
                h8v ah = *(const h8v*)&Ap[frag_off((w & 1) * 4 + mt, kh, lane)];
                #pragma unroll
                for (int nt = 0; nt < 6; ++nt)
                    acc[mt][nt] = __builtin_amdgcn_mfma_f32_16x16x32_f16(ah, bh_[nt], acc[mt][nt], 0, 0, 0);
            }
        }
    }

    // ---- epilogue: bias + b64 stores into xp2[d][G][t][g][m] ----
    const int col  = lane & 15;
    const int rowq = lane >> 4;          // C rows m = rowq*4 + reg  (= batch)
    float bias_v[6];
    #pragma unroll
    for (int nt = 0; nt < 6; ++nt) bias_v[nt] = bias[wn + nt * 16 + col];

    _Float16* obase = xp + (size_t)(d * 16 + G) * T_LEN * TPG;
    #pragma unroll
    for (int mt = 0; mt < 4; ++mt) {
        int t = tc * 8 + (w & 1) * 4 + mt;
        _Float16* ot = obase + (size_t)t * TPG;
        #pragma unroll
        for (int nt = 0; nt < 6; ++nt) {
            int g = wn + nt * 16 + col;
            h4v c = { (_Float16)(acc[mt][nt][0] + bias_v[nt]),
                      (_Float16)(acc[mt][nt][1] + bias_v[nt]),
                      (_Float16)(acc[mt][nt][2] + bias_v[nt]),
                      (_Float16)(acc[mt][nt][3] + bias_v[nt]) };
            *(h4v*)(ot + g * 16 + rowq * 4) = c;    // 8B, coalesced across wave
        }
    }
}

// ---------------------------------------------------------------------------
// Kernel 2: GRU scan via MFMA. One wave per (dir, 16-batch group) = 32 blocks.
// gh[16,192] = 24 mfma_16x16x32_f16 per step; W-fragments (96 regs) are MFMA
// operands -> AGPR residency is FREE. R8 BUG FIXED: current step's x is
// captured into xc[] BEFORE the prefetch ring slot is overwritten (R8 read
// step s+2's x in the pointwise — absmax 0.279).
// ---------------------------------------------------------------------------
__global__ __launch_bounds__(64, 1) void gru_scan(
    const _Float16* __restrict__ xp2,
    const float* __restrict__ Whf, const float* __restrict__ bhf,
    const float* __restrict__ Whb, const float* __restrict__ bhb,
    float* __restrict__ feat)
{
    const int lane = threadIdx.x;
    const int blk  = blockIdx.x;        // 0..31
    const int d    = blk >> 4;
    const int G    = blk & 15;
    const int col  = lane & 15;
    const int quad = lane >> 4;

    const float* Whh = d ? Whb : Whf;
    const float* bhh = d ? bhb : bhf;

    // B-fragments: tile tt -> gates n = (tt>>2)*64 + (tt&3)*16 + col
    h8v wb[12][2];
    f4v accb[12];     // bias pre-splatted as MFMA C-init
    int loff[12];     // per-lane xp2 offsets (same n ordering)
    #pragma unroll
    for (int tt = 0; tt < 12; ++tt) {
        const int n = (tt >> 2) * 64 + (tt & 3) * 16 + col;
        const float* wrow = Whh + (size_t)n * 64;
        #pragma unroll
        for (int c = 0; c < 2; ++c) {
            float4 w0 = *(const float4*)(wrow + c * 32 + quad * 8);
            float4 w1 = *(const float4*)(wrow + c * 32 + quad * 8 + 4);
            wb[tt][c] = h8v{(_Float16)w0.x, (_Float16)w0.y, (_Float16)w0.z, (_Float16)w0.w,
                            (_Float16)w1.x, (_Float16)w1.y, (_Float16)w1.z, (_Float16)w1.w};
        }
        float bn = bhh[n];
        accb[tt] = f4v{bn, bn, bn, bn};
        loff[tt] = n * 16 + quad * 4;
    }

    __shared__ _Float16 hs[16 * 72];    // [m][72] padded rows
    float hold[4][4];
    #pragma unroll
    for (int nt = 0; nt < 4; ++nt)
        #pragma unroll
        for (int reg = 0; reg < 4; ++reg) {
            hold[nt][reg] = 0.f;
            hs[(quad * 4 + reg) * 72 + nt * 16 + col] = (_Float16)0.f;
        }

    const long tstep = d ? -(long)TPG : (long)TPG;
    const _Float16* base = xp2 + (size_t)(d * 16 + G) * T_LEN * TPG
                               + (size_t)(d ? T_LEN - 1 : 0) * TPG;

    h4v px[2][12];
    #pragma unroll
    for (int tt = 0; tt < 12; ++tt) {
        px[0][tt] = *(const h4v*)(base + loff[tt]);
        px[1][tt] = *(const h4v*)(base + tstep + loff[tt]);
    }
    const _Float16* pnext = base + 2 * tstep;

    const int feat_b0   = (G * 16 + quad * 4) * 256;
    const int off_first = d ? 192 : 0;
    const int off_last  = d ? 64 : 128;

    for (int s = 0; s < T_LEN; s += 2) {
        #pragma unroll
        for (int j = 0; j < 2; ++j) {
            const int sj = s + j;

            // A-fragments from LDS h (previous step's state)
            h8v a0 = *(const h8v*)&hs[col * 72 + quad * 8];
            h8v a1 = *(const h8v*)&hs[col * 72 + 32 + quad * 8];

            f4v gh[12];
            #pragma unroll
            for (int tt = 0; tt < 12; ++tt) {
                f4v t0 = __builtin_amdgcn_mfma_f32_16x16x32_f16(a0, wb[tt][0], accb[tt], 0, 0, 0);
                gh[tt] = __builtin_amdgcn_mfma_f32_16x16x32_f16(a1, wb[tt][1], t0, 0, 0, 0);
            }

            // capture CURRENT step's x before overwriting the ring slot (R8 fix)
            h4v xc[12];
            #pragma unroll
            for (int tt = 0; tt < 12; ++tt) xc[tt] = px[j][tt];

            // refill this slot for step sj+2 (loads fly during pointwise)
            if (sj + 2 < T_LEN) {
                #pragma unroll
                for (int tt = 0; tt < 12; ++tt)
                    px[j][tt] = *(const h4v*)(pnext + loff[tt]);
                pnext += tstep;
            }

            // pointwise: lane owns (m = quad*4+reg, u = nt*16+col)
            #pragma unroll
            for (int nt = 0; nt < 4; ++nt) {
                #pragma unroll
                for (int reg = 0; reg < 4; ++reg) {
                    float ar = gh[nt][reg];
                    float az = gh[4 + nt][reg];
                    float an = gh[8 + nt][reg];
                    float xr = (float)xc[nt][reg];
                    float xz = (float)xc[4 + nt][reg];
                    float xn = (float)xc[8 + nt][reg];
                    float r = sigm_f(xr + ar);
                    float z = sigm_f(xz + az);
                    float n = tanh_f(xn + r * an);
                    float h = fmaf(z, hold[nt][reg] - n, n);
                    hold[nt][reg] = h;
                    hs[(quad * 4 + reg) * 72 + nt * 16 + col] = (_Float16)h;
                }
            }

            if (sj == 0) {
                #pragma unroll
                for (int nt = 0; nt < 4; ++nt)
                    #pragma unroll
                    for (int reg = 0; reg < 4; ++reg)
                        feat[feat_b0 + reg * 256 + off_first + nt * 16 + col] = hold[nt][reg];
            }
            if (sj == T_LEN - 1) {
                #pragma unroll
                for (int nt = 0; nt < 4; ++nt)
                    #pragma unroll
                    for (int reg = 0; reg < 4; ++reg)
                        feat[feat_b0 + reg * 256 + off_last + nt * 16 + col] = hold[nt][reg];
            }
        }
    }
}

// ---------------------------------------------------------------------------
// Kernel 3: MLP head. feat[b][256] -> 32 (LeakyReLU) -> 1
// ---------------------------------------------------------------------------
__global__ __launch_bounds__(64) void head_k(
    const float* __restrict__ feat,
    const float* __restrict__ W1, const float* __restrict__ b1,
    const float* __restrict__ W2, const float* __restrict__ b2,
    float* __restrict__ out)
{
    __shared__ float fs[256];
    const int b = blockIdx.x;
    const int tid = threadIdx.x;
    *(float4*)&fs[tid * 4] = *(const float4*)&feat[b * 256 + tid * 4];
    __syncthreads();
    float v = 0.f;
    if (tid < 32) {
        float a = b1[tid];
        const float4* Wv = (const float4*)(W1 + tid * 256);
        const float4* fv = (const float4*)fs;
        #pragma unroll 8
        for (int k = 0; k < 64; ++k) {
            float4 wv = Wv[k], f = fv[k];
            a += wv.x * f.x + wv.y * f.y + wv.z * f.z + wv.w * f.w;
        }
        a = a >= 0.f ? a : 0.01f * a;
        v = a * W2[tid];
    }
    #pragma unroll
    for (int off = 16; off > 0; off >>= 1) v += __shfl_down(v, off);
    if (tid == 0) out[b] = v + b2[0];
}

// ---------------------------------------------------------------------------
extern "C" void kernel_launch(void* const* d_in, const int* in_sizes, int n_in,
                              void* d_out, int out_size, void* d_ws, size_t ws_size,
                              hipStream_t stream)
{
    const float* x    = (const float*)d_in[0];
    const float* Wihf = (const float*)d_in[1];
    const float* Whhf = (const float*)d_in[2];
    const float* bihf = (const float*)d_in[3];
    const float* bhhf = (const float*)d_in[4];
    const float* Wihb = (const float*)d_in[5];
    const float* Whhb = (const float*)d_in[6];
    const float* bihb = (const float*)d_in[7];
    const float* bhhb = (const float*)d_in[8];
    const float* W1   = (const float*)d_in[9];
    const float* b1   = (const float*)d_in[10];
    const float* W2   = (const float*)d_in[11];
    const float* b2   = (const float*)d_in[12];
    float* out = (float*)d_out;

    _Float16* xp2  = (_Float16*)d_ws;                        // [d][G][t][g][16m], 100.7 MB
    float*    feat = (float*)((char*)d_ws + (size_t)2 * B_SZ * T_LEN * G3 * 2);

    proj_gemm<<<2048, 256, 0, stream>>>(x, Wihf, bihf, Wihb, bihb, xp2);
    gru_scan<<<32, 64, 0, stream>>>(xp2, Whhf, bhhf, Whhb, bhhb, feat);
    head_k<<<256, 64, 0, stream>>>(feat, W1, b1, W2, b2, out);
}

// Round 10
// 558.849 us; speedup vs baseline: 1.6565x; 1.6565x over previous
//
#include <hip/hip_runtime.h>
#include <hip/hip_bf16.h>
#include <math.h>

#define T_LEN 512
#define B_SZ  256
#define I_SZ  300
#define H_SZ  64
#define G3    192   // 3H
#define TPG   3072  // 192*16 h16 per t-slice of one group
#define HPAD  80    // hs row stride (h16) — 4-way worst case on b128 reads

typedef float    f4v __attribute__((ext_vector_type(4)));
typedef _Float16 h4v __attribute__((ext_vector_type(4)));
typedef _Float16 h8v __attribute__((ext_vector_type(8)));

__device__ __forceinline__ float sigm_f(float x) {
    return __builtin_amdgcn_rcpf(1.f + __expf(-x));
}
__device__ __forceinline__ float tanh_f(float x) {
    float a = fabsf(x);
    float e = __expf(2.f * a);
    float t = 1.f - 2.f * __builtin_amdgcn_rcpf(1.f + e);
    return copysignf(t, x);
}

// ---------------------------------------------------------------------------
// Kernel 1: input projection, f16 MFMA (UNCHANGED from R9 — its ~300 µs is
// the next target once its counters surface). xp2[d][G][t][g(192)][m(16)].
// ---------------------------------------------------------------------------
#define KC  64
#define NKC 5     // ceil(300/64)

__device__ __forceinline__ int stage_off(int j, int srow, int skq) {
    int g2 = (skq >> 1) & 3;
    return j * 1024 + (skq >> 3) * 512 + g2 * 128 + ((srow ^ (g2 << 1)) << 3) + (skq & 1) * 4;
}
__device__ __forceinline__ int frag_off(int tile, int kh, int lane) {
    int kgrp = lane >> 4, fr = lane & 15;
    return tile * 1024 + kh * 512 + kgrp * 128 + (((fr ^ (kgrp << 1))) << 3);
}

__global__ __launch_bounds__(256, 2) void proj_gemm(
    const float* __restrict__ x,
    const float* __restrict__ Wf, const float* __restrict__ bf,
    const float* __restrict__ Wb, const float* __restrict__ bb,
    _Float16* __restrict__ xp)
{
    __shared__ _Float16 Ap[8 * 1024];    // 16 KB
    __shared__ _Float16 Bp[12 * 1024];   // 24 KB

    const int tid = threadIdx.x;
    const int bid = blockIdx.x;          // 0..2047
    const int d   = bid >> 10;
    const int G   = (bid >> 6) & 15;     // batch group (16 b's)
    const int tc  = bid & 63;            // t-chunk (8 t's)

    const float* W    = d ? Wb : Wf;
    const float* bias = d ? bb : bf;

    const int srow = tid >> 4;           // 0..15  (= batch within group for A)
    const int skq  = tid & 15;           // k-quad (k' = skq*4)

    const int lane = tid & 63;
    const int w    = tid >> 6;           // 0..3
    const int wn   = (w >> 1) * 96;      // wave N offset

    f4v acc[4][6];
    #pragma unroll
    for (int mt = 0; mt < 4; ++mt)
        #pragma unroll
        for (int nt = 0; nt < 6; ++nt) acc[mt][nt] = (f4v)0.f;

    float4 av[8], bv[12];
    {
        const bool valid = (skq * 4) <= 296;
        #pragma unroll
        for (int j = 0; j < 8; ++j)
            av[j] = valid ? *(const float4*)(x + ((size_t)(G * 16 + srow) * T_LEN + tc * 8 + j) * I_SZ + skq * 4)
                          : float4{0.f, 0.f, 0.f, 0.f};
        #pragma unroll
        for (int j = 0; j < 12; ++j)
            bv[j] = valid ? *(const float4*)(W + (size_t)(j * 16 + srow) * I_SZ + skq * 4)
                          : float4{0.f, 0.f, 0.f, 0.f};
    }

    for (int kc = 0; kc < NKC; ++kc) {
        __syncthreads();

        #pragma unroll
        for (int j = 0; j < 8; ++j) {
            h4v c = { (_Float16)av[j].x, (_Float16)av[j].y,
                      (_Float16)av[j].z, (_Float16)av[j].w };
            *(h4v*)&Ap[stage_off(j, srow, skq)] = c;
        }
        #pragma unroll
        for (int j = 0; j < 12; ++j) {
            h4v c = { (_Float16)bv[j].x, (_Float16)bv[j].y,
                      (_Float16)bv[j].z, (_Float16)bv[j].w };
            *(h4v*)&Bp[stage_off(j, srow, skq)] = c;
        }
        __syncthreads();

        if (kc + 1 < NKC) {
            const int k0 = (kc + 1) * KC;
            const bool valid = (k0 + skq * 4) <= 296;
            #pragma unroll
            for (int j = 0; j < 8; ++j)
                av[j] = valid ? *(const float4*)(x + ((size_t)(G * 16 + srow) * T_LEN + tc * 8 + j) * I_SZ + k0 + skq * 4)
                              : float4{0.f, 0.f, 0.f, 0.f};
            #pragma unroll
            for (int j = 0; j < 12; ++j)
                bv[j] = valid ? *(const float4*)(W + (size_t)(j * 16 + srow) * I_SZ + k0 + skq * 4)
                              : float4{0.f, 0.f, 0.f, 0.f};
        }

        #pragma unroll
        for (int kh = 0; kh < 2; ++kh) {
            h8v bh_[6];
            #pragma unroll
            for (int nt = 0; nt < 6; ++nt)
                bh_[nt] = *(const h8v*)&Bp[frag_off((w >> 1) * 6 + nt, kh, lane)];
            #pragma unroll
            for (int mt = 0; mt < 4; ++mt) {
                h8v ah = *(const h8v*)&Ap[frag_off((w & 1) * 4 + mt, kh, lane)];
                #pragma unroll
                for (int nt = 0; nt < 6; ++nt)
                    acc[mt][nt] = __builtin_amdgcn_mfma_f32_16x16x32_f16(ah, bh_[nt], acc[mt][nt], 0, 0, 0);
            }
        }
    }

    const int col  = lane & 15;
    const int rowq = lane >> 4;
    float bias_v[6];
    #pragma unroll
    for (int nt = 0; nt < 6; ++nt) bias_v[nt] = bias[wn + nt * 16 + col];

    _Float16* obase = xp + (size_t)(d * 16 + G) * T_LEN * TPG;
    #pragma unroll
    for (int mt = 0; mt < 4; ++mt) {
        int t = tc * 8 + (w & 1) * 4 + mt;
        _Float16* ot = obase + (size_t)t * TPG;
        #pragma unroll
        for (int nt = 0; nt < 6; ++nt) {
            int g = wn + nt * 16 + col;
            h4v c = { (_Float16)(acc[mt][nt][0] + bias_v[nt]),
                      (_Float16)(acc[mt][nt][1] + bias_v[nt]),
                      (_Float16)(acc[mt][nt][2] + bias_v[nt]),
                      (_Float16)(acc[mt][nt][3] + bias_v[nt]) };
            *(h4v*)(ot + g * 16 + rowq * 4) = c;
        }
    }
}

// ---------------------------------------------------------------------------
// Kernel 2: GRU scan via MFMA, 32 blocks x 256 thr (4 waves).
// Wave w owns u-slice [16w,16w+16) across ALL 3 gates (tiles w, 4+w, 8+w):
// each lane's C-fragment (m=quad*4+reg, u=w*16+col) holds exactly the r/z/n
// triple its pointwise needs -> gh never leaves the wave (R9's 2900 cyc/step
// was one wave doing 24 MFMA + 16-batch pointwise solo). LDS carries only h:
// double-buffered, scatter b16 writes, contiguous b128 A-frag reads, ONE
// barrier per step.
// ---------------------------------------------------------------------------
__global__ __launch_bounds__(256) void gru_scan(
    const _Float16* __restrict__ xp2,
    const float* __restrict__ Whf, const float* __restrict__ bhf,
    const float* __restrict__ Whb, const float* __restrict__ bhb,
    float* __restrict__ feat)
{
    const int tid  = threadIdx.x;
    const int lane = tid & 63;
    const int w    = tid >> 6;          // wave = u-slice
    const int blk  = blockIdx.x;        // 0..31
    const int d    = blk >> 4;
    const int G    = blk & 15;
    const int col  = lane & 15;
    const int quad = lane >> 4;
    const int u    = w * 16 + col;      // hidden unit owned by this lane

    const float* Whh = d ? Whb : Whf;
    const float* bhh = d ? bhb : bhf;

    // B-frags for gates g=0(r),1(z),2(n): row n = g*64 + u
    h8v wb[3][2];
    f4v accb[3];
    int loff[3];
    #pragma unroll
    for (int g = 0; g < 3; ++g) {
        const int n = g * 64 + u;
        const float* wrow = Whh + (size_t)n * 64;
        #pragma unroll
        for (int c = 0; c < 2; ++c) {
            float4 w0 = *(const float4*)(wrow + c * 32 + quad * 8);
            float4 w1 = *(const float4*)(wrow + c * 32 + quad * 8 + 4);
            wb[g][c] = h8v{(_Float16)w0.x, (_Float16)w0.y, (_Float16)w0.z, (_Float16)w0.w,
                           (_Float16)w1.x, (_Float16)w1.y, (_Float16)w1.z, (_Float16)w1.w};
        }
        float bn = bhh[n];
        accb[g] = f4v{bn, bn, bn, bn};
        loff[g] = n * 16 + quad * 4;    // b64 slice: m = quad*4 .. +3
    }

    __shared__ _Float16 hs[2][16 * HPAD];
    for (int i = tid; i < 16 * HPAD; i += 256) hs[0][i] = (_Float16)0.f;
    float hold[4] = {0.f, 0.f, 0.f, 0.f};

    const long tstep = d ? -(long)TPG : (long)TPG;
    const _Float16* base = xp2 + (size_t)(d * 16 + G) * T_LEN * TPG
                               + (size_t)(d ? T_LEN - 1 : 0) * TPG;

    h4v px[2][3];
    #pragma unroll
    for (int g = 0; g < 3; ++g) {
        px[0][g] = *(const h4v*)(base + loff[g]);
        px[1][g] = *(const h4v*)(base + tstep + loff[g]);
    }
    const _Float16* pnext = base + 2 * tstep;

    const int off_first = d ? 192 : 0;
    const int off_last  = d ? 64 : 128;

    __syncthreads();

    for (int s = 0; s < T_LEN; s += 2) {
        #pragma unroll
        for (int j = 0; j < 2; ++j) {
            const int sj = s + j;
            const _Float16* hrd = hs[j];        // read buffer (s+j parity)
            _Float16*       hwr = hs[j ^ 1];

            // A-frags: h[m=col][k] from LDS (contiguous 16B per lane)
            h8v a0 = *(const h8v*)&hrd[col * HPAD + quad * 8];
            h8v a1 = *(const h8v*)&hrd[col * HPAD + 32 + quad * 8];

            f4v gh[3];
            #pragma unroll
            for (int g = 0; g < 3; ++g) {
                f4v t0 = __builtin_amdgcn_mfma_f32_16x16x32_f16(a0, wb[g][0], accb[g], 0, 0, 0);
                gh[g]  = __builtin_amdgcn_mfma_f32_16x16x32_f16(a1, wb[g][1], t0, 0, 0, 0);
            }

            // capture current x before ring-slot refill (R8 lesson)
            h4v xc[3];
            #pragma unroll
            for (int g = 0; g < 3; ++g) xc[g] = px[j][g];
            if (sj + 2 < T_LEN) {
                #pragma unroll
                for (int g = 0; g < 3; ++g)
                    px[j][g] = *(const h4v*)(pnext + loff[g]);
                pnext += tstep;
            }

            // pointwise: 4 elements (m = quad*4+reg, u) — all operands local
            #pragma unroll
            for (int reg = 0; reg < 4; ++reg) {
                float r = sigm_f((float)xc[0][reg] + gh[0][reg]);
                float z = sigm_f((float)xc[1][reg] + gh[1][reg]);
                float n = tanh_f((float)xc[2][reg] + r * gh[2][reg]);
                float h = fmaf(z, hold[reg] - n, n);
                hold[reg] = h;
                hwr[(quad * 4 + reg) * HPAD + u] = (_Float16)h;
            }

            if (sj == 0) {
                #pragma unroll
                for (int reg = 0; reg < 4; ++reg)
                    feat[(G * 16 + quad * 4 + reg) * 256 + off_first + u] = hold[reg];
            }
            if (sj == T_LEN - 1) {
                #pragma unroll
                for (int reg = 0; reg < 4; ++reg)
                    feat[(G * 16 + quad * 4 + reg) * 256 + off_last + u] = hold[reg];
            }
            __syncthreads();   // writes of h_s visible before next step's reads
        }
    }
}

// ---------------------------------------------------------------------------
// Kernel 3: MLP head. feat[b][256] -> 32 (LeakyReLU) -> 1
// ---------------------------------------------------------------------------
__global__ __launch_bounds__(64) void head_k(
    const float* __restrict__ feat,
    const float* __restrict__ W1, const float* __restrict__ b1,
    const float* __restrict__ W2, const float* __restrict__ b2,
    float* __restrict__ out)
{
    __shared__ float fs[256];
    const int b = blockIdx.x;
    const int tid = threadIdx.x;
    *(float4*)&fs[tid * 4] = *(const float4*)&feat[b * 256 + tid * 4];
    __syncthreads();
    float v = 0.f;
    if (tid < 32) {
        float a = b1[tid];
        const float4* Wv = (const float4*)(W1 + tid * 256);
        const float4* fv = (const float4*)fs;
        #pragma unroll 8
        for (int k = 0; k < 64; ++k) {
            float4 wv = Wv[k], f = fv[k];
            a += wv.x * f.x + wv.y * f.y + wv.z * f.z + wv.w * f.w;
        }
        a = a >= 0.f ? a : 0.01f * a;
        v = a * W2[tid];
    }
    #pragma unroll
    for (int off = 16; off > 0; off >>= 1) v += __shfl_down(v, off);
    if (tid == 0) out[b] = v + b2[0];
}

// ---------------------------------------------------------------------------
extern "C" void kernel_launch(void* const* d_in, const int* in_sizes, int n_in,
                              void* d_out, int out_size, void* d_ws, size_t ws_size,
                              hipStream_t stream)
{
    const float* x    = (const float*)d_in[0];
    const float* Wihf = (const float*)d_in[1];
    const float* Whhf = (const float*)d_in[2];
    const float* bihf = (const float*)d_in[3];
    const float* bhhf = (const float*)d_in[4];
    const float* Wihb = (const float*)d_in[5];
    const float* Whhb = (const float*)d_in[6];
    const float* bihb = (const float*)d_in[7];
    const float* bhhb = (const float*)d_in[8];
    const float* W1   = (const float*)d_in[9];
    const float* b1   = (const float*)d_in[10];
    const float* W2   = (const float*)d_in[11];
    const float* b2   = (const float*)d_in[12];
    float* out = (float*)d_out;

    _Float16* xp2  = (_Float16*)d_ws;                        // [d][G][t][g][16m], 100.7 MB
    float*    feat = (float*)((char*)d_ws + (size_t)2 * B_SZ * T_LEN * G3 * 2);

    proj_gemm<<<2048, 256, 0, stream>>>(x, Wihf, bihf, Wihb, bihb, xp2);
    gru_scan<<<32, 256, 0, stream>>>(xp2, Whhf, bhhf, Whhb, bhhb, feat);
    head_k<<<256, 64, 0, stream>>>(feat, W1, b1, W2, b2, out);
}